// Round 18
// baseline (271.763 us; speedup 1.0000x reference)
//
#include <hip/hip_runtime.h>
#include <stdint.h>

#define DEV __device__ __forceinline__

typedef __attribute__((ext_vector_type(8))) __bf16 bf16x8;
typedef __attribute__((ext_vector_type(4))) __bf16 bf16x4;
typedef __attribute__((ext_vector_type(4))) float f32x4;

DEV unsigned short f2bf(float f){
  union { float fv; unsigned u; } v; v.fv = f;
  unsigned r = v.u + 0x7fffu + ((v.u >> 16) & 1u);
  return (unsigned short)(r >> 16);
}

// async global->LDS, 16B per lane. LDS dest = wave-uniform base + lane*16.
DEV void gload16(const void* g, void* l){
  __builtin_amdgcn_global_load_lds((const __attribute__((address_space(1))) void*)g,
                                   (__attribute__((address_space(3))) void*)l,
                                   16, 0, 0);
}

// ---------------- fp32 -> bf16 convert: all three tensors in ONE launch ----------------
__global__ void k_cvt3(const float* __restrict__ x,    unsigned short* __restrict__ xb,
                       const float* __restrict__ wqkv, unsigned short* __restrict__ wqkvb,
                       const float* __restrict__ wout, unsigned short* __restrict__ woutb){
  const int bid = blockIdx.x;
  const float* src; unsigned short* dst; int base;
  if (bid < 8192)       { src = x;    dst = xb;    base = bid; }
  else if (bid < 11264) { src = wqkv; dst = wqkvb; base = bid - 8192; }
  else                  { src = wout; dst = woutb; base = bid - 11264; }
  const int i = (base*256 + threadIdx.x) << 2;
  const float4 v = *(const float4*)(src + i);
  ushort4 o;
  o.x = f2bf(v.x); o.y = f2bf(v.y); o.z = f2bf(v.z); o.w = f2bf(v.w);
  *(ushort4*)(dst + i) = o;
}

// ---------------- GEMM: C[M,N] = A[M,K] * B[N,K]^T, K=1024 ----------------
// 128x128 tile, BK=64, 4 waves (wave tile 64x64 -> MFMA:ds_read = 2:1),
// double-buffered LDS (64KB -> 2 blocks/CU), counted-vmcnt pipeline
// (stage t+1 before compute t; vmcnt(8), raw s_barrier).
template<int MODE>
__launch_bounds__(256, 2)
__global__ void k_gemm(const unsigned short* __restrict__ A,
                       const unsigned short* __restrict__ Bm,
                       const float* __restrict__ bias,
                       float* __restrict__ outF,
                       unsigned short* __restrict__ Qm,
                       unsigned short* __restrict__ Km,
                       unsigned short* __restrict__ VTm)
{
  __shared__ unsigned short As[2][128*64];   // 32KB
  __shared__ unsigned short Bs[2][128*64];   // 32KB
  const int tid  = threadIdx.x;
  const int lane = tid & 63;
  const int wid  = tid >> 6;     // 0..3
  const int wr   = wid >> 1;     // 0..1 (64-row stripes)
  const int wc   = wid & 1;      // 0..1 (64-col stripes)
  const int l15  = lane & 15;
  const int l4   = lane >> 4;
  // XCD-aware mapping: XCD x owns row-panels [8x,8x+8) (A-chunk 2MB, L2-resident)
  const int wg  = blockIdx.x;
  const int by  = (wg & 7)*8 + ((wg >> 3) & 7);
  const int bx  = wg >> 6;
  const int r0  = by * 128;
  const int c0  = bx * 128;

  f32x4 acc[4][4];
#pragma unroll
  for (int m = 0; m < 4; ++m)
#pragma unroll
    for (int n = 0; n < 4; ++n)
      acc[m][n] = (f32x4){0.f, 0.f, 0.f, 0.f};

  auto STAGE = [&](int buf, int kt){
    const int k0 = kt << 6;
#pragma unroll
    for (int i = 0; i < 4; ++i){               // A: 128x64x2B = 16KB = 4 rounds of 256x16B
      const int s = i*256 + tid;
      const int row = s >> 3;
      const int cg = (s & 7) ^ (row & 7);
      gload16(A + (size_t)(r0 + row)*1024 + k0 + cg*8, (void*)(&As[buf][s*8]));
    }
#pragma unroll
    for (int i = 0; i < 4; ++i){               // B: 128x64
      const int s = i*256 + tid;
      const int row = s >> 3;
      const int cg = (s & 7) ^ (row & 7);
      gload16(Bm + (size_t)(c0 + row)*1024 + k0 + cg*8, (void*)(&Bs[buf][s*8]));
    }
  };

  auto COMPUTE = [&](int buf){
#pragma unroll
    for (int kk = 0; kk < 2; ++kk){
      bf16x8 af[4], bf[4];
#pragma unroll
      for (int m = 0; m < 4; ++m){
        const int row = wr*64 + m*16 + l15;
        const int ch  = (kk*4 + l4) ^ (row & 7);
        af[m] = *(const bf16x8*)(&As[buf][row*64 + ch*8]);
      }
#pragma unroll
      for (int n = 0; n < 4; ++n){
        const int row = wc*64 + n*16 + l15;
        const int ch  = (kk*4 + l4) ^ (row & 7);
        bf[n] = *(const bf16x8*)(&Bs[buf][row*64 + ch*8]);
      }
      __builtin_amdgcn_s_setprio(1);
#pragma unroll
      for (int m = 0; m < 4; ++m)
#pragma unroll
        for (int n = 0; n < 4; ++n)
          acc[m][n] = __builtin_amdgcn_mfma_f32_16x16x32_bf16(af[m], bf[n], acc[m][n], 0, 0, 0);
      __builtin_amdgcn_s_setprio(0);
    }
  };

  STAGE(0, 0);
  for (int t = 0; t < 15; ++t){
    const int cur = t & 1;
    STAGE(cur ^ 1, t + 1);                     // 8 new loads -> up to 16 outstanding
    asm volatile("s_waitcnt vmcnt(8)" ::: "memory");   // tile t landed; t+1 in flight
    asm volatile("s_barrier" ::: "memory");
    COMPUTE(cur);
    asm volatile("s_waitcnt lgkmcnt(0)" ::: "memory");
    asm volatile("s_barrier" ::: "memory");
  }
  asm volatile("s_waitcnt vmcnt(0)" ::: "memory");
  asm volatile("s_barrier" ::: "memory");
  COMPUTE(1);

  if (MODE == 0){
#pragma unroll
    for (int n = 0; n < 4; ++n){
      const int f     = c0 + wc*64 + n*16 + l15;
      const float bs  = bias[f];
      const int which = f >> 10;
      const int fi    = f & 1023;
      const int h     = fi >> 6;
      const int d     = fi & 63;
#pragma unroll
      for (int m = 0; m < 4; ++m){
        const int rb = r0 + wr*64 + m*16 + (l4 << 2);
#pragma unroll
        for (int j = 0; j < 4; ++j){
          const int r = rb + j;
          const int t = r >> 2;
          const int b = r & 3;
          float v = acc[m][n][j] + bs;
          if (which == 0) v *= 0.18033688f;    // Dh^-0.5 * log2(e)
          const unsigned short bv = f2bf(v);
          const int bh = b*16 + h;
          if (which == 0)      Qm [((size_t)bh*2048 + t)*64 + d] = bv;
          else if (which == 1) Km [((size_t)bh*2048 + t)*64 + d] = bv;
          else                 VTm[((size_t)bh*64 + d)*2048 + t] = bv;
        }
      }
    }
  } else {
#pragma unroll
    for (int m = 0; m < 4; ++m){
      const int rb = r0 + wr*64 + m*16 + (l4 << 2);
#pragma unroll
      for (int n = 0; n < 4; ++n){
        const int f    = c0 + wc*64 + n*16 + l15;
        const float bs = bias[f];
#pragma unroll
        for (int j = 0; j < 4; ++j)
          outF[(size_t)(rb + j)*1024 + f] = acc[m][n][j] + bs;
      }
    }
  }
}

// ---------------- PV fused with softmax denominator (round-12 verbatim) ----------------
// 8 waves x 32 q-rows (t-tile 256): K/V LDS fragments reused across 2 q-subtiles.
// Stage-early + single __syncthreads per tile. Swapped QK^T, exp2, packed P-write,
// wave-private Ws rows.
__launch_bounds__(512)
__global__ void k_pv(const unsigned short* __restrict__ Qm,
                     const unsigned short* __restrict__ Km,
                     const unsigned short* __restrict__ VTm,
                     float* __restrict__ linv,
                     unsigned short* __restrict__ ctx)
{
  __shared__ unsigned short Ws[256*64];     // 32KB (wave-private 32-row stripes)
  __shared__ unsigned short Ks[2][64*64];   // 16KB dbuf
  __shared__ unsigned short Vs[2][64*64];   // 16KB dbuf  (V^T tile: [d][s])
  const int tid = threadIdx.x, lane = tid & 63, wid = tid >> 6;  // wid 0..7
  const int l15 = lane & 15, l4 = lane >> 4;
  // XCD swizzle: XCD x owns bh in [8x, 8x+8) -> K+V footprint 4MB = its L2
  const int wg = blockIdx.x;                // 512
  const int slot = wg >> 3;                 // 0..63
  const int bh = (wg & 7)*8 + (slot >> 3);
  const int t0 = (slot & 7) * 256;
  const unsigned short* Qb = Qm  + (size_t)bh*131072;
  const unsigned short* Kb = Km  + (size_t)bh*131072;
  const unsigned short* Vb = VTm + (size_t)bh*131072;

  // stage K/V tile 0 (512 lanes = 64 rows x 8 chunks)
  {
    const int s = tid;
    const int row = s >> 3;
    const int cg = (s & 7) ^ (row & 7);
    gload16(Kb + (size_t)row*64 + cg*8, (void*)(Ks[0] + s*8));
    gload16(Vb + (size_t)row*2048 + cg*8, (void*)(Vs[0] + s*8));
  }
  // Q fragments direct from global: 2 q-subtiles of 16 rows each
  bf16x8 aq[2][2];
#pragma unroll
  for (int qs = 0; qs < 2; ++qs)
#pragma unroll
    for (int kk = 0; kk < 2; ++kk)
      aq[qs][kk] = *(const bf16x8*)(Qb + (size_t)(t0 + wid*32 + qs*16 + l15)*64 + (kk*4 + l4)*8);
  __syncthreads();

  f32x4 oacc[2][4];
#pragma unroll
  for (int qs = 0; qs < 2; ++qs)
#pragma unroll
    for (int n = 0; n < 4; ++n) oacc[qs][n] = (f32x4){0.f,0.f,0.f,0.f};
  float lacc[2] = {0.f, 0.f};
  const int rx = l15 & 7;

  for (int s0 = 0; s0 < 2048; s0 += 64){
    const int cur = (s0 >> 6) & 1;
    if (s0 + 64 < 2048){
      const int s = tid;
      const int row = s >> 3;
      const int cg = (s & 7) ^ (row & 7);
      gload16(Kb + (size_t)(s0 + 64 + row)*64 + cg*8, (void*)(Ks[cur^1] + s*8));
      gload16(Vb + (size_t)row*2048 + (s0 + 64) + cg*8, (void*)(Vs[cur^1] + s*8));
    }
    // swapped QK^T: K-fragments loaded once per n, reused for both q-subtiles
#pragma unroll
    for (int n = 0; n < 4; ++n){
      bf16x8 ak[2];
#pragma unroll
      for (int kk = 0; kk < 2; ++kk){
        const int ch = (kk*4 + l4) ^ rx;           // (sr&7) == rx
        ak[kk] = *(const bf16x8*)(Ks[cur] + (n*16 + l15)*64 + ch*8);
      }
#pragma unroll
      for (int qs = 0; qs < 2; ++qs){
        f32x4 sacc = (f32x4){0.f,0.f,0.f,0.f};
        sacc = __builtin_amdgcn_mfma_f32_16x16x32_bf16(ak[0], aq[qs][0], sacc, 0, 0, 0);
        sacc = __builtin_amdgcn_mfma_f32_16x16x32_bf16(ak[1], aq[qs][1], sacc, 0, 0, 0);
        f32x4 pv;
        pv[0] = __builtin_amdgcn_exp2f(sacc[0]);
        pv[1] = __builtin_amdgcn_exp2f(sacc[1]);
        pv[2] = __builtin_amdgcn_exp2f(sacc[2]);
        pv[3] = __builtin_amdgcn_exp2f(sacc[3]);
        lacc[qs] += (pv[0] + pv[1]) + (pv[2] + pv[3]);
        const bf16x4 pb = __builtin_convertvector(pv, bf16x4);
        const int wrow = wid*32 + qs*16 + l15;
        const int g = (n*4 + l4) ^ (rx << 1);      // 8B-granule swizzle
        *(bf16x4*)(Ws + wrow*64 + g*4) = pb;
      }
    }
    // read P rows back as PV A-operand (wave-private rows)
    bf16x8 aw[2][2];
#pragma unroll
    for (int qs = 0; qs < 2; ++qs)
#pragma unroll
      for (int kk = 0; kk < 2; ++kk){
        const int c = (kk*4 + l4) ^ rx;            // matching 16B-chunk swizzle
        aw[qs][kk] = *(const bf16x8*)(Ws + (wid*32 + qs*16 + l15)*64 + c*8);
      }
    // PV: V-fragments loaded once, reused for both q-subtiles
#pragma unroll
    for (int n = 0; n < 4; ++n){
#pragma unroll
      for (int kk = 0; kk < 2; ++kk){
        const int ch = (kk*4 + l4) ^ rx;           // (dr&7) == rx
        const bf16x8 bv = *(const bf16x8*)(Vs[cur] + (n*16 + l15)*64 + ch*8);
#pragma unroll
        for (int qs = 0; qs < 2; ++qs)
          oacc[qs][n] = __builtin_amdgcn_mfma_f32_16x16x32_bf16(aw[qs][kk], bv, oacc[qs][n], 0, 0, 0);
      }
    }
    __syncthreads();   // drains stage loads (issued a full compute-phase ago; cheap)
  }

  const int b = bh >> 4, h = bh & 15;
#pragma unroll
  for (int qs = 0; qs < 2; ++qs){
    lacc[qs] += __shfl_xor(lacc[qs], 16);
    lacc[qs] += __shfl_xor(lacc[qs], 32);
    const float rl = 1.0f / lacc[qs];
    if (lane < 16)
      linv[(size_t)bh*2048 + t0 + wid*32 + qs*16 + lane] = rl;
    float rlj[4];
#pragma unroll
    for (int j = 0; j < 4; ++j)
      rlj[j] = __shfl(rl, (l4 << 2) + j);
#pragma unroll
    for (int n = 0; n < 4; ++n){
#pragma unroll
      for (int j = 0; j < 4; ++j){
        const int t = t0 + wid*32 + qs*16 + (l4 << 2) + j;
        const int d = n*16 + l15;
        ctx[((size_t)t*4 + b)*1024 + h*64 + d] = f2bf(oacc[qs][n][j] * rlj[j]);
      }
    }
  }
}

// ---------------- avg weights (round-11 verbatim) ----------------
// 4 waves x 32 q-rows (t-tile 128), s-tile 128. K dbuf with counted-vmcnt pipeline;
// per-head reg loads (aq/lj) issued BEFORE the stage so vmcnt(4) covers both.
__launch_bounds__(256)
__global__ void k_avg(const unsigned short* __restrict__ Qm,
                      const unsigned short* __restrict__ Km,
                      const float* __restrict__ linv,
                      float* __restrict__ avg)
{
  __shared__ unsigned short Ks[2][128*64];   // 32KB
  const int tid = threadIdx.x, lane = tid & 63, wid = tid >> 6;
  const int l15 = lane & 15, l4 = lane >> 4;
  const int wg = blockIdx.x;                 // 1024
  const int slot = wg >> 3;                  // 0..127
  const int combo = (wg & 7) + 8*(slot >> 4);   // 0..63
  const int b   = combo >> 4;
  const int s0  = (combo & 15) * 128;
  const int t0  = (slot & 15) * 128;
  const int rx  = l15 & 7;

  float wacc[2][8][4];
#pragma unroll
  for (int qs = 0; qs < 2; ++qs)
#pragma unroll
    for (int n = 0; n < 8; ++n)
#pragma unroll
      for (int j = 0; j < 4; ++j) wacc[qs][n][j] = 0.f;

  // prologue: stage head 0 K tile
  {
    const unsigned short* Kb = Km + (size_t)(b*16)*131072;
#pragma unroll
    for (int i = 0; i < 4; ++i){
      const int s = i*256 + tid;
      const int row = s >> 3;
      const int cg = (s & 7) ^ (row & 7);
      gload16(Kb + (size_t)(s0 + row)*64 + cg*8, (void*)(Ks[0] + s*8));
    }
  }

  for (int h = 0; h < 16; ++h){
    const int cur = h & 1;
    const int bh = b*16 + h;
    const unsigned short* Qb = Qm + (size_t)bh*131072;

    // reg loads FIRST (older than the stage loads below -> vmcnt(4) covers them)
    bf16x8 aq[2][2];
#pragma unroll
    for (int qs = 0; qs < 2; ++qs)
#pragma unroll
      for (int kk = 0; kk < 2; ++kk)
        aq[qs][kk] = *(const bf16x8*)(Qb + (size_t)(t0 + wid*32 + qs*16 + l15)*64 + (kk*4 + l4)*8);

    float4 lj[2];
#pragma unroll
    for (int qs = 0; qs < 2; ++qs){
      lj[qs] = *(const float4*)(linv + (size_t)bh*2048 + t0 + wid*32 + qs*16 + (l4 << 2));
      lj[qs].x *= 0.0625f; lj[qs].y *= 0.0625f; lj[qs].z *= 0.0625f; lj[qs].w *= 0.0625f;
    }

    if (h < 15){
      const unsigned short* Kb = Km + (size_t)(b*16 + h + 1)*131072;
#pragma unroll
      for (int i = 0; i < 4; ++i){
        const int s = i*256 + tid;
        const int row = s >> 3;
        const int cg = (s & 7) ^ (row & 7);
        gload16(Kb + (size_t)(s0 + row)*64 + cg*8, (void*)(Ks[cur^1] + s*8));
      }
      asm volatile("s_waitcnt vmcnt(4)" ::: "memory");   // head h K-tile + aq/lj landed
    } else {
      asm volatile("s_waitcnt vmcnt(0)" ::: "memory");
    }
    asm volatile("s_barrier" ::: "memory");

#pragma unroll
    for (int n = 0; n < 8; ++n){
      bf16x8 bk[2];
#pragma unroll
      for (int kk = 0; kk < 2; ++kk){
        const int ch = (kk*4 + l4) ^ rx;           // (row&7) == rx
        bk[kk] = *(const bf16x8*)(Ks[cur] + (n*16 + l15)*64 + ch*8);
      }
#pragma unroll
      for (int qs = 0; qs < 2; ++qs){
        f32x4 sacc = (f32x4){0.f,0.f,0.f,0.f};
        sacc = __builtin_amdgcn_mfma_f32_16x16x32_bf16(aq[qs][0], bk[0], sacc, 0, 0, 0);
        sacc = __builtin_amdgcn_mfma_f32_16x16x32_bf16(aq[qs][1], bk[1], sacc, 0, 0, 0);
        wacc[qs][n][0] += __builtin_amdgcn_exp2f(sacc[0]) * lj[qs].x;
        wacc[qs][n][1] += __builtin_amdgcn_exp2f(sacc[1]) * lj[qs].y;
        wacc[qs][n][2] += __builtin_amdgcn_exp2f(sacc[2]) * lj[qs].z;
        wacc[qs][n][3] += __builtin_amdgcn_exp2f(sacc[3]) * lj[qs].w;
      }
    }
    asm volatile("s_waitcnt lgkmcnt(0)" ::: "memory");
    asm volatile("s_barrier" ::: "memory");        // reads of Ks[cur] done before overwrite
  }

#pragma unroll
  for (int qs = 0; qs < 2; ++qs)
#pragma unroll
    for (int n = 0; n < 8; ++n)
#pragma unroll
      for (int j = 0; j < 4; ++j){
        const int t = t0 + wid*32 + qs*16 + (l4 << 2) + j;
        const int s = s0 + n*16 + l15;
        avg[((size_t)b*2048 + t)*2048 + s] = wacc[qs][n][j];
      }
}

extern "C" void kernel_launch(void* const* d_in, const int* in_sizes, int n_in,
                              void* d_out, int out_size, void* d_ws, size_t ws_size,
                              hipStream_t stream)
{
  const float* x    = (const float*)d_in[0];
  const float* wqkv = (const float*)d_in[1];
  const float* bqkv = (const float*)d_in[2];
  const float* wout = (const float*)d_in[3];
  const float* bout = (const float*)d_in[4];
  float* out = (float*)d_out;

  char* ws = (char*)d_ws;
  unsigned short* xb    = (unsigned short*)(ws);
  unsigned short* wqkvb = (unsigned short*)(ws + ((size_t)16 << 20));
  unsigned short* woutb = (unsigned short*)(ws + ((size_t)24 << 20));
  unsigned short* Qm    = (unsigned short*)(ws + ((size_t)26 << 20));
  unsigned short* Km    = (unsigned short*)(ws + ((size_t)42 << 20));
  unsigned short* VTm   = (unsigned short*)(ws + ((size_t)58 << 20));
  unsigned short* ctx   = (unsigned short*)(ws + ((size_t)74 << 20));
  float* linv = (float*)(ws + ((size_t)90 << 20));

  k_cvt3<<<12288, 256, 0, stream>>>(x, xb, wqkv, wqkvb, wout, woutb);

  k_gemm<0><<<1536, 256, 0, stream>>>(xb, wqkvb, bqkv, nullptr, Qm, Km, VTm);
  k_pv     <<< 512, 512, 0, stream>>>(Qm, Km, VTm, linv, ctx);
  k_avg    <<<1024, 256, 0, stream>>>(Qm, Km, linv, out + 8388608);
  k_gemm<1><<< 512, 256, 0, stream>>>(ctx, woutb, bout, out, nullptr, nullptr, nullptr);
}

// Round 19
// 257.227 us; speedup vs baseline: 1.0565x; 1.0565x over previous
//
#include <hip/hip_runtime.h>
#include <stdint.h>

#define DEV __device__ __forceinline__

typedef __attribute__((ext_vector_type(8))) __bf16 bf16x8;
typedef __attribute__((ext_vector_type(4))) __bf16 bf16x4;
typedef __attribute__((ext_vector_type(4))) float f32x4;

DEV unsigned short f2bf(float f){
  union { float fv; unsigned u; } v; v.fv = f;
  unsigned r = v.u + 0x7fffu + ((v.u >> 16) & 1u);
  return (unsigned short)(r >> 16);
}

// async global->LDS, 16B per lane. LDS dest = wave-uniform base + lane*16.
DEV void gload16(const void* g, void* l){
  __builtin_amdgcn_global_load_lds((const __attribute__((address_space(1))) void*)g,
                                   (__attribute__((address_space(3))) void*)l,
                                   16, 0, 0);
}

// ---------------- fp32 -> bf16 convert: all three tensors in ONE launch ----------------
__global__ void k_cvt3(const float* __restrict__ x,    unsigned short* __restrict__ xb,
                       const float* __restrict__ wqkv, unsigned short* __restrict__ wqkvb,
                       const float* __restrict__ wout, unsigned short* __restrict__ woutb){
  const int bid = blockIdx.x;
  const float* src; unsigned short* dst; int base;
  if (bid < 8192)       { src = x;    dst = xb;    base = bid; }
  else if (bid < 11264) { src = wqkv; dst = wqkvb; base = bid - 8192; }
  else                  { src = wout; dst = woutb; base = bid - 11264; }
  const int i = (base*256 + threadIdx.x) << 2;
  const float4 v = *(const float4*)(src + i);
  ushort4 o;
  o.x = f2bf(v.x); o.y = f2bf(v.y); o.z = f2bf(v.z); o.w = f2bf(v.w);
  *(ushort4*)(dst + i) = o;
}

// ---------------- GEMM: C[M,N] = A[M,K] * B[N,K]^T, K=1024 ----------------
// 128x128 tile, BK=64, 8 waves (wave tile 32x64), double-buffered LDS (64KB -> 2 blocks/CU),
// counted-vmcnt pipeline (stage t+1 before compute t; vmcnt(4), raw s_barrier).
template<int MODE>
__launch_bounds__(512, 4)
__global__ void k_gemm(const unsigned short* __restrict__ A,
                       const unsigned short* __restrict__ Bm,
                       const float* __restrict__ bias,
                       float* __restrict__ outF,
                       unsigned short* __restrict__ Qm,
                       unsigned short* __restrict__ Km,
                       unsigned short* __restrict__ VTm)
{
  __shared__ unsigned short As[2][128*64];   // 32KB
  __shared__ unsigned short Bs[2][128*64];   // 32KB
  const int tid  = threadIdx.x;
  const int lane = tid & 63;
  const int wid  = tid >> 6;     // 0..7
  const int wr   = wid >> 1;     // 0..3 (32-row stripes)
  const int wc   = wid & 1;      // 0..1 (64-col stripes)
  const int l15  = lane & 15;
  const int l4   = lane >> 4;
  const int wg  = blockIdx.x;
  const int by  = (wg & 7)*8 + ((wg >> 3) & 7);
  const int bx  = wg >> 6;
  const int r0  = by * 128;
  const int c0  = bx * 128;

  f32x4 acc[2][4];
#pragma unroll
  for (int m = 0; m < 2; ++m)
#pragma unroll
    for (int n = 0; n < 4; ++n)
      acc[m][n] = (f32x4){0.f, 0.f, 0.f, 0.f};

  auto STAGE = [&](int buf, int kt){
    const int k0 = kt << 6;
#pragma unroll
    for (int i = 0; i < 2; ++i){
      const int s = i*512 + tid;
      const int row = s >> 3;
      const int cg = (s & 7) ^ (row & 7);
      gload16(A + (size_t)(r0 + row)*1024 + k0 + cg*8, (void*)(&As[buf][s*8]));
    }
#pragma unroll
    for (int i = 0; i < 2; ++i){
      const int s = i*512 + tid;
      const int row = s >> 3;
      const int cg = (s & 7) ^ (row & 7);
      gload16(Bm + (size_t)(c0 + row)*1024 + k0 + cg*8, (void*)(&Bs[buf][s*8]));
    }
  };

  auto COMPUTE = [&](int buf){
#pragma unroll
    for (int kk = 0; kk < 2; ++kk){
      bf16x8 af[2], bf[4];
#pragma unroll
      for (int m = 0; m < 2; ++m){
        const int row = wr*32 + m*16 + l15;
        const int ch  = (kk*4 + l4) ^ (row & 7);
        af[m] = *(const bf16x8*)(&As[buf][row*64 + ch*8]);
      }
#pragma unroll
      for (int n = 0; n < 4; ++n){
        const int row = wc*64 + n*16 + l15;
        const int ch  = (kk*4 + l4) ^ (row & 7);
        bf[n] = *(const bf16x8*)(&Bs[buf][row*64 + ch*8]);
      }
      __builtin_amdgcn_s_setprio(1);
#pragma unroll
      for (int m = 0; m < 2; ++m)
#pragma unroll
        for (int n = 0; n < 4; ++n)
          acc[m][n] = __builtin_amdgcn_mfma_f32_16x16x32_bf16(af[m], bf[n], acc[m][n], 0, 0, 0);
      __builtin_amdgcn_s_setprio(0);
    }
  };

  STAGE(0, 0);
  for (int t = 0; t < 15; ++t){
    const int cur = t & 1;
    STAGE(cur ^ 1, t + 1);
    asm volatile("s_waitcnt vmcnt(4)" ::: "memory");
    asm volatile("s_barrier" ::: "memory");
    COMPUTE(cur);
    asm volatile("s_waitcnt lgkmcnt(0)" ::: "memory");
    asm volatile("s_barrier" ::: "memory");
  }
  asm volatile("s_waitcnt vmcnt(0)" ::: "memory");
  asm volatile("s_barrier" ::: "memory");
  COMPUTE(1);

  if (MODE == 0){
#pragma unroll
    for (int n = 0; n < 4; ++n){
      const int f     = c0 + wc*64 + n*16 + l15;
      const float bs  = bias[f];
      const int which = f >> 10;
      const int fi    = f & 1023;
      const int h     = fi >> 6;
      const int d     = fi & 63;
#pragma unroll
      for (int m = 0; m < 2; ++m){
        const int rb = r0 + wr*32 + m*16 + (l4 << 2);
#pragma unroll
        for (int j = 0; j < 4; ++j){
          const int r = rb + j;
          const int t = r >> 2;
          const int b = r & 3;
          float v = acc[m][n][j] + bs;
          if (which == 0) v *= 0.18033688f;      // Dh^-0.5 * log2(e)
          const unsigned short bv = f2bf(v);
          const int bh = b*16 + h;
          if (which == 0)      Qm [((size_t)bh*2048 + t)*64 + d] = bv;
          else if (which == 1) Km [((size_t)bh*2048 + t)*64 + d] = bv;
          else                 VTm[((size_t)bh*64 + d)*2048 + t] = bv;
        }
      }
    }
  } else {
#pragma unroll
    for (int m = 0; m < 2; ++m){
      const int rb = r0 + wr*32 + m*16 + (l4 << 2);
#pragma unroll
      for (int n = 0; n < 4; ++n){
        const int f    = c0 + wc*64 + n*16 + l15;
        const float bs = bias[f];
#pragma unroll
        for (int j = 0; j < 4; ++j)
          outF[(size_t)(rb + j)*1024 + f] = acc[m][n][j] + bs;
      }
    }
  }
}

// ---------------- PV fused with softmax denominator (round-12 verbatim) ----------------
// 8 waves x 32 q-rows (t-tile 256): K/V LDS fragments reused across 2 q-subtiles.
// Stage-early + single __syncthreads per tile. Swapped QK^T, exp2, packed P-write,
// wave-private Ws rows.
__launch_bounds__(512)
__global__ void k_pv(const unsigned short* __restrict__ Qm,
                     const unsigned short* __restrict__ Km,
                     const unsigned short* __restrict__ VTm,
                     float* __restrict__ linv,
                     unsigned short* __restrict__ ctx)
{
  __shared__ unsigned short Ws[256*64];     // 32KB (wave-private 32-row stripes)
  __shared__ unsigned short Ks[2][64*64];   // 16KB dbuf
  __shared__ unsigned short Vs[2][64*64];   // 16KB dbuf  (V^T tile: [d][s])
  const int tid = threadIdx.x, lane = tid & 63, wid = tid >> 6;  // wid 0..7
  const int l15 = lane & 15, l4 = lane >> 4;
  // XCD swizzle: XCD x owns bh in [8x, 8x+8) -> K+V footprint 4MB = its L2
  const int wg = blockIdx.x;                // 512
  const int slot = wg >> 3;                 // 0..63
  const int bh = (wg & 7)*8 + (slot >> 3);
  const int t0 = (slot & 7) * 256;
  const unsigned short* Qb = Qm  + (size_t)bh*131072;
  const unsigned short* Kb = Km  + (size_t)bh*131072;
  const unsigned short* Vb = VTm + (size_t)bh*131072;

  // stage K/V tile 0 (512 lanes = 64 rows x 8 chunks)
  {
    const int s = tid;
    const int row = s >> 3;
    const int cg = (s & 7) ^ (row & 7);
    gload16(Kb + (size_t)row*64 + cg*8, (void*)(Ks[0] + s*8));
    gload16(Vb + (size_t)row*2048 + cg*8, (void*)(Vs[0] + s*8));
  }
  // Q fragments direct from global: 2 q-subtiles of 16 rows each
  bf16x8 aq[2][2];
#pragma unroll
  for (int qs = 0; qs < 2; ++qs)
#pragma unroll
    for (int kk = 0; kk < 2; ++kk)
      aq[qs][kk] = *(const bf16x8*)(Qb + (size_t)(t0 + wid*32 + qs*16 + l15)*64 + (kk*4 + l4)*8);
  __syncthreads();

  f32x4 oacc[2][4];
#pragma unroll
  for (int qs = 0; qs < 2; ++qs)
#pragma unroll
    for (int n = 0; n < 4; ++n) oacc[qs][n] = (f32x4){0.f,0.f,0.f,0.f};
  float lacc[2] = {0.f, 0.f};
  const int rx = l15 & 7;

  for (int s0 = 0; s0 < 2048; s0 += 64){
    const int cur = (s0 >> 6) & 1;
    if (s0 + 64 < 2048){
      const int s = tid;
      const int row = s >> 3;
      const int cg = (s & 7) ^ (row & 7);
      gload16(Kb + (size_t)(s0 + 64 + row)*64 + cg*8, (void*)(Ks[cur^1] + s*8));
      gload16(Vb + (size_t)row*2048 + (s0 + 64) + cg*8, (void*)(Vs[cur^1] + s*8));
    }
    // swapped QK^T: K-fragments loaded once per n, reused for both q-subtiles
#pragma unroll
    for (int n = 0; n < 4; ++n){
      bf16x8 ak[2];
#pragma unroll
      for (int kk = 0; kk < 2; ++kk){
        const int ch = (kk*4 + l4) ^ rx;           // (sr&7) == rx
        ak[kk] = *(const bf16x8*)(Ks[cur] + (n*16 + l15)*64 + ch*8);
      }
#pragma unroll
      for (int qs = 0; qs < 2; ++qs){
        f32x4 sacc = (f32x4){0.f,0.f,0.f,0.f};
        sacc = __builtin_amdgcn_mfma_f32_16x16x32_bf16(ak[0], aq[qs][0], sacc, 0, 0, 0);
        sacc = __builtin_amdgcn_mfma_f32_16x16x32_bf16(ak[1], aq[qs][1], sacc, 0, 0, 0);
        f32x4 pv;
        pv[0] = __builtin_amdgcn_exp2f(sacc[0]);
        pv[1] = __builtin_amdgcn_exp2f(sacc[1]);
        pv[2] = __builtin_amdgcn_exp2f(sacc[2]);
        pv[3] = __builtin_amdgcn_exp2f(sacc[3]);
        lacc[qs] += (pv[0] + pv[1]) + (pv[2] + pv[3]);
        const bf16x4 pb = __builtin_convertvector(pv, bf16x4);
        const int wrow = wid*32 + qs*16 + l15;
        const int g = (n*4 + l4) ^ (rx << 1);      // 8B-granule swizzle
        *(bf16x4*)(Ws + wrow*64 + g*4) = pb;
      }
    }
    // read P rows back as PV A-operand (wave-private rows)
    bf16x8 aw[2][2];
#pragma unroll
    for (int qs = 0; qs < 2; ++qs)
#pragma unroll
      for (int kk = 0; kk < 2; ++kk){
        const int c = (kk*4 + l4) ^ rx;            // matching 16B-chunk swizzle
        aw[qs][kk] = *(const bf16x8*)(Ws + (wid*32 + qs*16 + l15)*64 + c*8);
      }
    // PV: V-fragments loaded once, reused for both q-subtiles
#pragma unroll
    for (int n = 0; n < 4; ++n){
#pragma unroll
      for (int kk = 0; kk < 2; ++kk){
        const int ch = (kk*4 + l4) ^ rx;           // (dr&7) == rx
        const bf16x8 bv = *(const bf16x8*)(Vs[cur] + (n*16 + l15)*64 + ch*8);
#pragma unroll
        for (int qs = 0; qs < 2; ++qs)
          oacc[qs][n] = __builtin_amdgcn_mfma_f32_16x16x32_bf16(aw[qs][kk], bv, oacc[qs][n], 0, 0, 0);
      }
    }
    __syncthreads();   // drains stage loads (issued a full compute-phase ago; cheap)
  }

  const int b = bh >> 4, h = bh & 15;
#pragma unroll
  for (int qs = 0; qs < 2; ++qs){
    lacc[qs] += __shfl_xor(lacc[qs], 16);
    lacc[qs] += __shfl_xor(lacc[qs], 32);
    const float rl = 1.0f / lacc[qs];
    if (lane < 16)
      linv[(size_t)bh*2048 + t0 + wid*32 + qs*16 + lane] = rl;
    float rlj[4];
#pragma unroll
    for (int j = 0; j < 4; ++j)
      rlj[j] = __shfl(rl, (l4 << 2) + j);
#pragma unroll
    for (int n = 0; n < 4; ++n){
#pragma unroll
      for (int j = 0; j < 4; ++j){
        const int t = t0 + wid*32 + qs*16 + (l4 << 2) + j;
        const int d = n*16 + l15;
        ctx[((size_t)t*4 + b)*1024 + h*64 + d] = f2bf(oacc[qs][n][j] * rlj[j]);
      }
    }
  }
}

// ---------------- avg weights (round-11 verbatim) ----------------
// 4 waves x 32 q-rows (t-tile 128), s-tile 128. K dbuf with counted-vmcnt pipeline;
// per-head reg loads (aq/lj) issued BEFORE the stage so vmcnt(4) covers both.
__launch_bounds__(256)
__global__ void k_avg(const unsigned short* __restrict__ Qm,
                      const unsigned short* __restrict__ Km,
                      const float* __restrict__ linv,
                      float* __restrict__ avg)
{
  __shared__ unsigned short Ks[2][128*64];   // 32KB
  const int tid = threadIdx.x, lane = tid & 63, wid = tid >> 6;
  const int l15 = lane & 15, l4 = lane >> 4;
  const int wg = blockIdx.x;                 // 1024
  const int slot = wg >> 3;                  // 0..127
  const int combo = (wg & 7) + 8*(slot >> 4);   // 0..63
  const int b   = combo >> 4;
  const int s0  = (combo & 15) * 128;
  const int t0  = (slot & 15) * 128;
  const int rx  = l15 & 7;

  float wacc[2][8][4];
#pragma unroll
  for (int qs = 0; qs < 2; ++qs)
#pragma unroll
    for (int n = 0; n < 8; ++n)
#pragma unroll
      for (int j = 0; j < 4; ++j) wacc[qs][n][j] = 0.f;

  // prologue: stage head 0 K tile
  {
    const unsigned short* Kb = Km + (size_t)(b*16)*131072;
#pragma unroll
    for (int i = 0; i < 4; ++i){
      const int s = i*256 + tid;
      const int row = s >> 3;
      const int cg = (s & 7) ^ (row & 7);
      gload16(Kb + (size_t)(s0 + row)*64 + cg*8, (void*)(Ks[0] + s*8));
    }
  }

  for (int h = 0; h < 16; ++h){
    const int cur = h & 1;
    const int bh = b*16 + h;
    const unsigned short* Qb = Qm + (size_t)bh*131072;

    // reg loads FIRST (older than the stage loads below -> vmcnt(4) covers them)
    bf16x8 aq[2][2];
#pragma unroll
    for (int qs = 0; qs < 2; ++qs)
#pragma unroll
      for (int kk = 0; kk < 2; ++kk)
        aq[qs][kk] = *(const bf16x8*)(Qb + (size_t)(t0 + wid*32 + qs*16 + l15)*64 + (kk*4 + l4)*8);

    float4 lj[2];
#pragma unroll
    for (int qs = 0; qs < 2; ++qs){
      lj[qs] = *(const float4*)(linv + (size_t)bh*2048 + t0 + wid*32 + qs*16 + (l4 << 2));
      lj[qs].x *= 0.0625f; lj[qs].y *= 0.0625f; lj[qs].z *= 0.0625f; lj[qs].w *= 0.0625f;
    }

    if (h < 15){
      const unsigned short* Kb = Km + (size_t)(b*16 + h + 1)*131072;
#pragma unroll
      for (int i = 0; i < 4; ++i){
        const int s = i*256 + tid;
        const int row = s >> 3;
        const int cg = (s & 7) ^ (row & 7);
        gload16(Kb + (size_t)(s0 + row)*64 + cg*8, (void*)(Ks[cur^1] + s*8));
      }
      asm volatile("s_waitcnt vmcnt(4)" ::: "memory");   // head h K-tile + aq/lj landed
    } else {
      asm volatile("s_waitcnt vmcnt(0)" ::: "memory");
    }
    asm volatile("s_barrier" ::: "memory");

#pragma unroll
    for (int n = 0; n < 8; ++n){
      bf16x8 bk[2];
#pragma unroll
      for (int kk = 0; kk < 2; ++kk){
        const int ch = (kk*4 + l4) ^ rx;           // (row&7) == rx
        bk[kk] = *(const bf16x8*)(Ks[cur] + (n*16 + l15)*64 + ch*8);
      }
#pragma unroll
      for (int qs = 0; qs < 2; ++qs){
        f32x4 sacc = (f32x4){0.f,0.f,0.f,0.f};
        sacc = __builtin_amdgcn_mfma_f32_16x16x32_bf16(aq[qs][0], bk[0], sacc, 0, 0, 0);
        sacc = __builtin_amdgcn_mfma_f32_16x16x32_bf16(aq[qs][1], bk[1], sacc, 0, 0, 0);
        wacc[qs][n][0] += __builtin_amdgcn_exp2f(sacc[0]) * lj[qs].x;
        wacc[qs][n][1] += __builtin_amdgcn_exp2f(sacc[1]) * lj[qs].y;
        wacc[qs][n][2] += __builtin_amdgcn_exp2f(sacc[2]) * lj[qs].z;
        wacc[qs][n][3] += __builtin_amdgcn_exp2f(sacc[3]) * lj[qs].w;
      }
    }
    asm volatile("s_waitcnt lgkmcnt(0)" ::: "memory");
    asm volatile("s_barrier" ::: "memory");        // reads of Ks[cur] done before overwrite
  }

#pragma unroll
  for (int qs = 0; qs < 2; ++qs)
#pragma unroll
    for (int n = 0; n < 8; ++n)
#pragma unroll
      for (int j = 0; j < 4; ++j){
        const int t = t0 + wid*32 + qs*16 + (l4 << 2) + j;
        const int s = s0 + n*16 + l15;
        avg[((size_t)b*2048 + t)*2048 + s] = wacc[qs][n][j];
      }
}

extern "C" void kernel_launch(void* const* d_in, const int* in_sizes, int n_in,
                              void* d_out, int out_size, void* d_ws, size_t ws_size,
                              hipStream_t stream)
{
  const float* x    = (const float*)d_in[0];
  const float* wqkv = (const float*)d_in[1];
  const float* bqkv = (const float*)d_in[2];
  const float* wout = (const float*)d_in[3];
  const float* bout = (const float*)d_in[4];
  float* out = (float*)d_out;

  char* ws = (char*)d_ws;
  unsigned short* xb    = (unsigned short*)(ws);
  unsigned short* wqkvb = (unsigned short*)(ws + ((size_t)16 << 20));
  unsigned short* woutb = (unsigned short*)(ws + ((size_t)24 << 20));
  unsigned short* Qm    = (unsigned short*)(ws + ((size_t)26 << 20));
  unsigned short* Km    = (unsigned short*)(ws + ((size_t)42 << 20));
  unsigned short* VTm   = (unsigned short*)(ws + ((size_t)58 << 20));
  unsigned short* ctx   = (unsigned short*)(ws + ((size_t)74 << 20));
  float* linv = (float*)(ws + ((size_t)90 << 20));

  k_cvt3<<<12288, 256, 0, stream>>>(x, xb, wqkv, wqkvb, wout, woutb);

  k_gemm<0><<<1536, 512, 0, stream>>>(xb, wqkvb, bqkv, nullptr, Qm, Km, VTm);
  k_pv     <<< 512, 512, 0, stream>>>(Qm, Km, VTm, linv, ctx);
  k_avg    <<<1024, 256, 0, stream>>>(Qm, Km, linv, out + 8388608);
  k_gemm<1><<< 512, 512, 0, stream>>>(ctx, woutb, bout, out, nullptr, nullptr, nullptr);
}